// Round 1
// 680.896 us; speedup vs baseline: 1.0097x; 1.0097x over previous
//
#include <hip/hip_runtime.h>
#include <hip/hip_bf16.h>

// Problem constants (reference: T,B,D,H = 1024,512,128,128)
#define T_STEPS 1024
#define BATCH   512
#define DIM     128
#define G3      384          // 3*H gate rows
#define NCHUNK  (T_STEPS/8)  // 128 chunks of 8 steps
#define GI_STRIDE 129        // padded gi row stride (f32x4 units): rows 2064B apart
                             // -> +4 bank shift/row, breaks the 8-way conflict on
                             // producer gi writes (rows 4q+r were 2048B = 0-shift)

typedef __attribute__((ext_vector_type(8))) short bf16x8;
typedef __attribute__((ext_vector_type(4))) float f32x4;

#define LOG2E  1.44269504f   // r,z gate rows pre-scaled by log2(e)
#define LOG2E2 2.88539008f   // n gate rows pre-scaled by 2*log2(e)
#define NV_CLAMP 43.28f      // 15 * 2*log2e (tanh saturation clamp, scaled units)

__device__ __forceinline__ short f2bf(float f) {
  unsigned u = __builtin_bit_cast(unsigned, f);
  u += 0x7FFFu + ((u >> 16) & 1u);   // round-to-nearest-even
  return (short)(u >> 16);
}

// LDS-only barrier: drains LDS ops for cross-wave visibility but does NOT
// drain vmcnt -> producer global prefetch stays in flight across steps.
__device__ __forceinline__ void block_sync_lds() {
  asm volatile("s_waitcnt lgkmcnt(0)\n\ts_barrier" ::: "memory");
}

// ---------------------------------------------------------------------------
// Prep: Wc = W_ih @ W1 (bf16), W_hh -> bf16, bc = W_ih @ b1 + b_ih (fp32).
// All r/z rows scaled by log2e, n rows by 2*log2e, so the GRU gate math uses
// raw v_exp_f32 (exp2) with no scaling muls on the critical path.
// Also emits bhh_s = b_hh * sg (scaled copy used by both producer & consumer).
// ---------------------------------------------------------------------------
__global__ void prep_kernel(const float* __restrict__ W1, const float* __restrict__ b1,
                            const float* __restrict__ W_ih, const float* __restrict__ W_hh,
                            const float* __restrict__ b_ih, const float* __restrict__ b_hh,
                            short* __restrict__ wc_bf, short* __restrict__ whh_bf,
                            float* __restrict__ bc, float* __restrict__ bhh_s) {
  const int g = blockIdx.x;
  const int d = threadIdx.x;
  const float sg = (g < 256) ? LOG2E : LOG2E2;
  float acc = 0.f;
  #pragma unroll 4
  for (int k = 0; k < 128; ++k)
    acc = fmaf(W_ih[g * 128 + k], W1[k * 128 + d], acc);
  wc_bf[g * 128 + d]  = f2bf(acc * sg);
  whh_bf[g * 128 + d] = f2bf(W_hh[g * 128 + d] * sg);

  __shared__ float red[128];
  red[d] = W_ih[g * 128 + d] * b1[d];
  __syncthreads();
  #pragma unroll
  for (int s = 64; s > 0; s >>= 1) {
    if (d < s) red[d] += red[d + s];
    __syncthreads();
  }
  if (d == 0) {
    bc[g]    = (red[0] + b_ih[g]) * sg;
    bhh_s[g] = b_hh[g] * sg;
  }
}

// ---------------------------------------------------------------------------
// Main GRU kernel. 256 blocks (2 chains) x 512 threads (8 waves, 2/SIMD).
// Waves 0-3 = CONSUMERS. Wave w owns h-cols [32w, 32w+32) = two 16-tiles x 3
// gates = 6 N-tiles = 24 MFMA/step. DUPLICATE-ROW A-frag: A rows 0-7 carry
// h[chain0], rows 8-15 h[chain1] (lane reads hbuf[c>>3]). D reg0 of quads
// {0,1,2,3} then holds {ch0,ch0,ch1,ch1} results, so quad parity selects the
// column half and EVERY lane does exactly one gate evaluation:
//   lane(q,c): chain = q>>1, col = 32w + 16*(q&1) + c.
// Per-step MFMA schedule: g-outer (r group, z group, sigmoids, n group) with
// split-K accumulators (kt{0,1} and kt{2,3}), so dependent MFMAs are spaced 4
// issues (~77cyc) apart and the r/z sigmoids overlap the n-group issue window.
// Consumers run at s_setprio(1): role-split producer/consumer is the T5-
// favorable regime; producer bursts must not steal issue slots from the
// recurrence-critical wave.
// gi prefetched to registers for the whole 8-step chunk (8 x b128 / lane).
// Waves 4-7 = PRODUCERS: gi for chunk c+1 during chunk c (M=16 = 8 steps x
// 2 chains), double-buffered gi (GI_STRIDE-padded rows); x prefetched one
// chunk ahead; biases folded; first-kt MFMA consumes a zero C directly.
// mfma_f32_16x16x32_bf16 layouts (m89-verified):
//   A[m=lane&15][k=quad*8+j], B[k=quad*8+j][n=lane&15], D: col=lane&15,row=quad*4+reg
// ---------------------------------------------------------------------------
__global__ __launch_bounds__(512, 2) void gru_kernel(
    const float* __restrict__ x,       // [T][B][D]
    const float* __restrict__ bhh_s,   // [384] scaled b_hh
    const short* __restrict__ wc_bf,   // [384][128] bf16 (scaled)
    const short* __restrict__ whh_bf,  // [384][128] bf16 (scaled)
    const float* __restrict__ bc,      // [384] (scaled)
    float* __restrict__ out)           // [B][H]
{
  const int tid = threadIdx.x;
  const int w   = tid >> 6;       // wave 0..7
  const int l   = tid & 63;
  const int q   = l >> 4;         // quad
  const int c   = l & 15;         // col-in-tile / A-row
  const int b0  = blockIdx.x * 2;

  __shared__ f32x4 gi4[2 * 16 * GI_STRIDE];  // [buf][m=2*step+chain][gatecol] padded, ~64.5 KB
  __shared__ short hbuf[2][2][128];          // [parity][chain][j] bf16

  const f32x4 zero4 = {0.f, 0.f, 0.f, 0.f};

  if (w < 4) {
    // ================= CONSUMER =================
    const int half = q & 1;                    // 0 -> Tt0 cols, 1 -> Tt1 cols
    const int ch   = q >> 1;                   // this lane's chain
    const int colX = w * 32 + (half << 4) + c; // this lane's hidden col

    bf16x8 Bh[3][2][4];
    #pragma unroll
    for (int g = 0; g < 3; ++g)
      #pragma unroll
      for (int Tt = 0; Tt < 2; ++Tt)
        #pragma unroll
        for (int kt = 0; kt < 4; ++kt)
          Bh[g][Tt][kt] = *(const bf16x8*)(whh_bf +
              (g * 128 + w * 32 + Tt * 16 + c) * 128 + kt * 32 + q * 8);
    const float bhn = bhh_s[256 + colX];       // scaled by 2*log2e

    ((short*)hbuf)[tid] = 0;        // tids 0..255 zero hbuf[0][*][*] exactly
    float hp = 0.f;
    __syncthreads();

    // A-row c -> chain c>>3 (rows 0-7: chain0, 8-15: chain1), broadcast reads
    const short* hb0 = &hbuf[0][c >> 3][q * 8];
    const short* hb1 = &hbuf[1][c >> 3][q * 8];

    __builtin_amdgcn_s_setprio(1);
    for (int cc = 0; cc < NCHUNK; ++cc) {
      // chunk-level gi prefetch: one b128 per step for this lane
      f32x4 gi[8];
      {
        const f32x4* gp = gi4 + (cc & 1) * (16 * GI_STRIDE) + ch * GI_STRIDE + colX;
        #pragma unroll
        for (int s = 0; s < 8; ++s) gi[s] = gp[2 * s * GI_STRIDE];
      }
      #pragma unroll
      for (int s = 0; s < 8; ++s) {
        const short* hb = (s & 1) ? hb1 : hb0;
        bf16x8 Ah[4];
        #pragma unroll
        for (int kt = 0; kt < 4; ++kt)
          Ah[kt] = *(const bf16x8*)(hb + kt * 32);

        // ---- g=0 (r): 4 independent depth-2 chains, dependents 4 issues apart
        f32x4 r0A = __builtin_amdgcn_mfma_f32_16x16x32_bf16(Ah[0], Bh[0][0][0], zero4, 0, 0, 0);
        f32x4 r1A = __builtin_amdgcn_mfma_f32_16x16x32_bf16(Ah[0], Bh[0][1][0], zero4, 0, 0, 0);
        f32x4 r0B = __builtin_amdgcn_mfma_f32_16x16x32_bf16(Ah[2], Bh[0][0][2], zero4, 0, 0, 0);
        f32x4 r1B = __builtin_amdgcn_mfma_f32_16x16x32_bf16(Ah[2], Bh[0][1][2], zero4, 0, 0, 0);
        r0A = __builtin_amdgcn_mfma_f32_16x16x32_bf16(Ah[1], Bh[0][0][1], r0A, 0, 0, 0);
        r1A = __builtin_amdgcn_mfma_f32_16x16x32_bf16(Ah[1], Bh[0][1][1], r1A, 0, 0, 0);
        r0B = __builtin_amdgcn_mfma_f32_16x16x32_bf16(Ah[3], Bh[0][0][3], r0B, 0, 0, 0);
        r1B = __builtin_amdgcn_mfma_f32_16x16x32_bf16(Ah[3], Bh[0][1][3], r1B, 0, 0, 0);
        // ---- g=1 (z)
        f32x4 z0A = __builtin_amdgcn_mfma_f32_16x16x32_bf16(Ah[0], Bh[1][0][0], zero4, 0, 0, 0);
        f32x4 z1A = __builtin_amdgcn_mfma_f32_16x16x32_bf16(Ah[0], Bh[1][1][0], zero4, 0, 0, 0);
        f32x4 z0B = __builtin_amdgcn_mfma_f32_16x16x32_bf16(Ah[2], Bh[1][0][2], zero4, 0, 0, 0);
        f32x4 z1B = __builtin_amdgcn_mfma_f32_16x16x32_bf16(Ah[2], Bh[1][1][2], zero4, 0, 0, 0);
        z0A = __builtin_amdgcn_mfma_f32_16x16x32_bf16(Ah[1], Bh[1][0][1], z0A, 0, 0, 0);
        z1A = __builtin_amdgcn_mfma_f32_16x16x32_bf16(Ah[1], Bh[1][1][1], z1A, 0, 0, 0);
        z0B = __builtin_amdgcn_mfma_f32_16x16x32_bf16(Ah[3], Bh[1][0][3], z0B, 0, 0, 0);
        z1B = __builtin_amdgcn_mfma_f32_16x16x32_bf16(Ah[3], Bh[1][1][3], z1B, 0, 0, 0);

        // r,z sigmoids overlap the n-group MFMA issue window (weights carry log2e)
        const float ghr = half ? (r1A[0] + r1B[0]) : (r0A[0] + r0B[0]);
        const float ghz = half ? (z1A[0] + z1B[0]) : (z0A[0] + z0B[0]);
        const float rg = __builtin_amdgcn_rcpf(1.f + __builtin_amdgcn_exp2f(-(gi[s][0] + ghr)));
        const float zg = __builtin_amdgcn_rcpf(1.f + __builtin_amdgcn_exp2f(-(gi[s][1] + ghz)));

        // ---- g=2 (n)
        f32x4 n0A = __builtin_amdgcn_mfma_f32_16x16x32_bf16(Ah[0], Bh[2][0][0], zero4, 0, 0, 0);
        f32x4 n1A = __builtin_amdgcn_mfma_f32_16x16x32_bf16(Ah[0], Bh[2][1][0], zero4, 0, 0, 0);
        f32x4 n0B = __builtin_amdgcn_mfma_f32_16x16x32_bf16(Ah[2], Bh[2][0][2], zero4, 0, 0, 0);
        f32x4 n1B = __builtin_amdgcn_mfma_f32_16x16x32_bf16(Ah[2], Bh[2][1][2], zero4, 0, 0, 0);
        n0A = __builtin_amdgcn_mfma_f32_16x16x32_bf16(Ah[1], Bh[2][0][1], n0A, 0, 0, 0);
        n1A = __builtin_amdgcn_mfma_f32_16x16x32_bf16(Ah[1], Bh[2][1][1], n1A, 0, 0, 0);
        n0B = __builtin_amdgcn_mfma_f32_16x16x32_bf16(Ah[3], Bh[2][0][3], n0B, 0, 0, 0);
        n1B = __builtin_amdgcn_mfma_f32_16x16x32_bf16(Ah[3], Bh[2][1][3], n1B, 0, 0, 0);
        const float ghn = half ? (n1A[0] + n1B[0]) : (n0A[0] + n0B[0]);

        // n in 2*log2e units: tanh(nv) = 1 - 2/(exp2(nv_s)+1)
        float nv = gi[s][2] + rg * (ghn + bhn);
        nv = fminf(fmaxf(nv, -NV_CLAMP), NV_CLAMP);
        const float e  = __builtin_amdgcn_exp2f(nv);
        const float nn = 1.f - 2.f * __builtin_amdgcn_rcpf(e + 1.f);
        const float h  = zg * (hp - nn) + nn;
        hp = h;
        hbuf[(s & 1) ^ 1][ch][colX] = f2bf(h);
        block_sync_lds();
      }
    }
    __builtin_amdgcn_s_setprio(0);
    out[(size_t)(b0 + ch) * DIM + colX] = hp;
  } else {
    // ================= PRODUCER =================
    const int w4 = w - 4;
    const int jg0 = w4 * 32 + c, jg1 = jg0 + 16;
    bf16x8 Bc[3][2][4];
    #pragma unroll
    for (int g = 0; g < 3; ++g)
      #pragma unroll
      for (int Tt = 0; Tt < 2; ++Tt)
        #pragma unroll
        for (int kt = 0; kt < 4; ++kt)
          Bc[g][Tt][kt] = *(const bf16x8*)(wc_bf +
              (g * 128 + w4 * 32 + Tt * 16 + c) * 128 + kt * 32 + q * 8);
    const float fr0 = bc[jg0]       + bhh_s[jg0];
    const float fz0 = bc[128 + jg0] + bhh_s[128 + jg0];
    const float fn0 = bc[256 + jg0];
    const float fr1 = bc[jg1]       + bhh_s[jg1];
    const float fz1 = bc[128 + jg1] + bhh_s[128 + jg1];
    const float fn1 = bc[256 + jg1];

    const int trel = c >> 1, chn = c & 1;   // A-row m = c = 2*trel + chn
    f32x4 xv[8];

    // ---- pre-phase: build chunk 0 into buf 0, then prefetch chunk 1
    {
      const float* xb = x + ((size_t)trel * BATCH + (b0 + chn)) * DIM + q * 8;
      f32x4 xt[8];
      #pragma unroll
      for (int kt = 0; kt < 4; ++kt) {
        xt[2 * kt]     = *(const f32x4*)(xb + kt * 32);
        xt[2 * kt + 1] = *(const f32x4*)(xb + kt * 32 + 4);
      }
      bf16x8 Ax[4];
      #pragma unroll
      for (int kt = 0; kt < 4; ++kt) {
        const f32x4 v0 = xt[2 * kt], v1 = xt[2 * kt + 1];
        bf16x8 a;
        a[0] = f2bf(v0[0]); a[1] = f2bf(v0[1]); a[2] = f2bf(v0[2]); a[3] = f2bf(v0[3]);
        a[4] = f2bf(v1[0]); a[5] = f2bf(v1[1]); a[6] = f2bf(v1[2]); a[7] = f2bf(v1[3]);
        Ax[kt] = a;
      }
      f32x4 ga[2][3];
      #pragma unroll
      for (int g = 0; g < 3; ++g) {
        ga[0][g] = __builtin_amdgcn_mfma_f32_16x16x32_bf16(Ax[0], Bc[g][0][0], zero4, 0, 0, 0);
        ga[1][g] = __builtin_amdgcn_mfma_f32_16x16x32_bf16(Ax[0], Bc[g][1][0], zero4, 0, 0, 0);
      }
      #pragma unroll
      for (int kt = 1; kt < 4; ++kt)
        #pragma unroll
        for (int g = 0; g < 3; ++g) {
          ga[0][g] = __builtin_amdgcn_mfma_f32_16x16x32_bf16(Ax[kt], Bc[g][0][kt], ga[0][g], 0, 0, 0);
          ga[1][g] = __builtin_amdgcn_mfma_f32_16x16x32_bf16(Ax[kt], Bc[g][1][kt], ga[1][g], 0, 0, 0);
        }
      #pragma unroll
      for (int r = 0; r < 4; ++r) {
        f32x4 vA = {ga[0][0][r] + fr0, ga[0][1][r] + fz0, ga[0][2][r] + fn0, 0.f};
        f32x4 vB = {ga[1][0][r] + fr1, ga[1][1][r] + fz1, ga[1][2][r] + fn1, 0.f};
        gi4[(4 * q + r) * GI_STRIDE + jg0] = vA;
        gi4[(4 * q + r) * GI_STRIDE + jg1] = vB;
      }
      const float* xb1 = x + ((size_t)(8 + trel) * BATCH + (b0 + chn)) * DIM + q * 8;
      #pragma unroll
      for (int kt = 0; kt < 4; ++kt) {
        xv[2 * kt]     = *(const f32x4*)(xb1 + kt * 32);
        xv[2 * kt + 1] = *(const f32x4*)(xb1 + kt * 32 + 4);
      }
    }
    __syncthreads();

    for (int cc = 0; cc < NCHUNK; ++cc) {
      const int tc = cc + 1;            // chunk being produced
      bf16x8 Ax[4];
      f32x4 ga[2][3];
      #pragma unroll
      for (int s = 0; s < 8; ++s) {
        if (tc < NCHUNK) {
          if (s == 0) {
            #pragma unroll
            for (int kt = 0; kt < 4; ++kt) {
              const f32x4 v0 = xv[2 * kt], v1 = xv[2 * kt + 1];
              bf16x8 a;
              a[0] = f2bf(v0[0]); a[1] = f2bf(v0[1]); a[2] = f2bf(v0[2]); a[3] = f2bf(v0[3]);
              a[4] = f2bf(v1[0]); a[5] = f2bf(v1[1]); a[6] = f2bf(v1[2]); a[7] = f2bf(v1[3]);
              Ax[kt] = a;
            }
          } else if (s == 1) {          // kt=0 consumes zero C directly (no re-zero movs)
            #pragma unroll
            for (int g = 0; g < 3; ++g) {
              ga[0][g] = __builtin_amdgcn_mfma_f32_16x16x32_bf16(Ax[0], Bc[g][0][0], zero4, 0, 0, 0);
              ga[1][g] = __builtin_amdgcn_mfma_f32_16x16x32_bf16(Ax[0], Bc[g][1][0], zero4, 0, 0, 0);
            }
          } else if (s <= 4) {
            const int kt = s - 1;
            #pragma unroll
            for (int g = 0; g < 3; ++g) {
              ga[0][g] = __builtin_amdgcn_mfma_f32_16x16x32_bf16(Ax[kt], Bc[g][0][kt], ga[0][g], 0, 0, 0);
              ga[1][g] = __builtin_amdgcn_mfma_f32_16x16x32_bf16(Ax[kt], Bc[g][1][kt], ga[1][g], 0, 0, 0);
            }
          } else if (s == 5) {
            if (tc + 1 < NCHUNK) {   // prefetch x for chunk tc+1 (stays in flight)
              const float* xb = x + ((size_t)((tc + 1) * 8 + trel) * BATCH + (b0 + chn)) * DIM + q * 8;
              #pragma unroll
              for (int kt = 0; kt < 4; ++kt) {
                xv[2 * kt]     = *(const f32x4*)(xb + kt * 32);
                xv[2 * kt + 1] = *(const f32x4*)(xb + kt * 32 + 4);
              }
            }
          } else if (s == 6) {
            #pragma unroll
            for (int r = 0; r < 4; ++r) {
              ga[0][0][r] += fr0; ga[0][1][r] += fz0; ga[0][2][r] += fn0;
              ga[1][0][r] += fr1; ga[1][1][r] += fz1; ga[1][2][r] += fn1;
            }
          } else {  // s == 7: publish gi for chunk tc
            f32x4* gb = gi4 + (tc & 1) * (16 * GI_STRIDE);
            #pragma unroll
            for (int r = 0; r < 4; ++r) {
              f32x4 vA = {ga[0][0][r], ga[0][1][r], ga[0][2][r], 0.f};
              f32x4 vB = {ga[1][0][r], ga[1][1][r], ga[1][2][r], 0.f};
              gb[(4 * q + r) * GI_STRIDE + jg0] = vA;
              gb[(4 * q + r) * GI_STRIDE + jg1] = vB;
            }
          }
        }
        block_sync_lds();
      }
    }
  }
}

// ---------------------------------------------------------------------------
extern "C" void kernel_launch(void* const* d_in, const int* in_sizes, int n_in,
                              void* d_out, int out_size, void* d_ws, size_t ws_size,
                              hipStream_t stream) {
  const float* x    = (const float*)d_in[0];
  const float* W1   = (const float*)d_in[1];
  const float* b1   = (const float*)d_in[2];
  const float* W_ih = (const float*)d_in[3];
  const float* W_hh = (const float*)d_in[4];
  const float* b_ih = (const float*)d_in[5];
  const float* b_hh = (const float*)d_in[6];
  float* out = (float*)d_out;

  char* ws = (char*)d_ws;
  short* wc_bf  = (short*)(ws);             // 384*128 bf16
  short* whh_bf = (short*)(ws + 98304);     // 384*128 bf16
  float* bc     = (float*)(ws + 196608);    // 384 fp32
  float* bhh_s  = (float*)(ws + 198144);    // 384 fp32 (scaled b_hh)

  prep_kernel<<<dim3(G3), dim3(128), 0, stream>>>(W1, b1, W_ih, W_hh, b_ih, b_hh,
                                                  wc_bf, whh_bf, bc, bhh_s);
  gru_kernel<<<dim3(BATCH / 2), dim3(512), 0, stream>>>(x, bhh_s, wc_bf, whh_bf, bc, out);
}